// Round 8
// baseline (313.172 us; speedup 1.0000x reference)
//
#include <hip/hip_runtime.h>

// Problem constants
#define NB 2
#define LL 2048
#define DD 1024
#define HH 16
#define NHH (NB*HH)          // 32 (n,h) pairs
#define LT (LL/64)           // 32 tiles of 64
#define KT16 (LL/16)         // 128 16-col tiles
#define CEXP 0.0450842200277801f   // log2(e)/32 : exp(x/32) == exp2(x*CEXP)

typedef __bf16 bf16x8 __attribute__((ext_vector_type(8)));
typedef unsigned short u16x8 __attribute__((ext_vector_type(8)));
typedef float f32x4 __attribute__((ext_vector_type(4)));

#define MFMA16 __builtin_amdgcn_mfma_f32_16x16x32_bf16
#define EXP2 __builtin_amdgcn_exp2f

__device__ __forceinline__ unsigned short f2bf(float f) {
    unsigned u = __float_as_uint(f);
    return (unsigned short)((u + 0x7fffu + ((u >> 16) & 1u)) >> 16);   // RNE
}
__device__ __forceinline__ float bf2f(unsigned short u) {
    return __uint_as_float(((unsigned)u) << 16);
}
__device__ __forceinline__ bf16x8 ldfrag(const unsigned short* p) {
    return *reinterpret_cast<const bf16x8*>(p);
}
__device__ __forceinline__ bf16x8 cvt8v(float4 a, float4 b) {
    u16x8 u;
    u[0]=f2bf(a.x); u[1]=f2bf(a.y); u[2]=f2bf(a.z); u[3]=f2bf(a.w);
    u[4]=f2bf(b.x); u[5]=f2bf(b.y); u[6]=f2bf(b.z); u[7]=f2bf(b.w);
    return __builtin_bit_cast(bf16x8, u);
}
__device__ __forceinline__ ushort4 pack4(f32x4 d, float sc) {
    ushort4 o;
    o.x = f2bf(d[0]*sc); o.y = f2bf(d[1]*sc); o.z = f2bf(d[2]*sc); o.w = f2bf(d[3]*sc);
    return o;
}

// ---------------------------------------------------------------------------
// K0: pre-convert Wk,Wq,Wv (fp32 64x64) into bf16 MFMA A-frags in the exact
// per-lane layout proj consumes.
// ---------------------------------------------------------------------------
__global__ __launch_bounds__(256) void wcvt_kernel(
    const float* __restrict__ Wk, const float* __restrict__ Wq,
    const float* __restrict__ Wv, unsigned short* __restrict__ wfrag)
{
    const int s = blockIdx.x * 256 + threadIdx.x;   // 0..1535
    const int m = s >> 9;
    const int rem = s & 511;
    const int f = rem >> 6;
    const int lane = rem & 63;
    const int n16 = lane & 15, quad = lane >> 4;
    const int mt = f >> 1, half = f & 1;
    const float* W = (m == 0) ? Wk : (m == 1) ? Wq : Wv;
    const float* p = W + (mt*16 + n16)*64 + quad*8 + half*32;
    float4 a = *reinterpret_cast<const float4*>(p);
    float4 b = *reinterpret_cast<const float4*>(p + 4);
    *reinterpret_cast<bf16x8*>(wfrag + (size_t)s * 8) = cvt8v(a, b);
}

// ---------------------------------------------------------------------------
// K1: projections via MFMA, D = W(A) . X^T(B). Grid (64,16,2):
// z=0 keys/query/okeys (+ediag); z=1 values/ovals. All loads issued up front.
// qb is pre-scaled by log2(e)/32.
// ---------------------------------------------------------------------------
__global__ __launch_bounds__(256) void proj_kernel(
    const float* __restrict__ values, const float* __restrict__ keys,
    const float* __restrict__ query,  const float* __restrict__ ovals,
    const float* __restrict__ okeys,  const unsigned short* __restrict__ wfrag,
    unsigned short* __restrict__ qb, unsigned short* __restrict__ okb,
    unsigned short* __restrict__ vb, unsigned short* __restrict__ ovb,
    float* __restrict__ ediag)
{
    const int t = threadIdx.x;
    const int w = t >> 6;
    const int lane = t & 63;
    const int n16 = lane & 15;
    const int quad = lane >> 4;
    const int h = blockIdx.y;
    const int row = blockIdx.x * 64 + w * 16 + n16;  // (n*L+l) == this lane's C-col
    const int nn = row >> 11;
    const int ll = row & 2047;
    const size_t xoff  = (size_t)row * DD + h * 64 + quad * 8;       // B-frag src
    const size_t qbase = (((size_t)(nn * HH + h)) * LL + ll) * 64;   // [nh][l][64]
    const size_t vbase = (size_t)row * DD + h * 64;                  // [row][1024]

    if (blockIdx.z == 0) {
        const float4* kp = reinterpret_cast<const float4*>(keys  + xoff);
        const float4* qp = reinterpret_cast<const float4*>(query + xoff);
        const float4* op = reinterpret_cast<const float4*>(okeys + xoff);
        float4 k0 = kp[0], k1 = kp[1], k2 = kp[8], k3 = kp[9];   // +0,+4,+32,+36
        float4 q0 = qp[0], q1 = qp[1], q2 = qp[8], q3 = qp[9];
        float4 o0 = op[0], o1 = op[1], o2 = op[8], o3 = op[9];
        bf16x8 wk[8], wq[8];
#pragma unroll
        for (int f = 0; f < 8; ++f) {
            wk[f] = ldfrag(wfrag + (size_t)(f * 64 + lane) * 8);
            wq[f] = ldfrag(wfrag + (size_t)((8 + f) * 64 + lane) * 8);
        }
        bf16x8 xk0 = cvt8v(k0, k1), xk1 = cvt8v(k2, k3);
        bf16x8 xq0 = cvt8v(q0, q1), xq1 = cvt8v(q2, q3);
        bf16x8 xo0 = cvt8v(o0, o1), xo1 = cvt8v(o2, o3);
        f32x4 ka[4], qa[4];
#pragma unroll
        for (int mt = 0; mt < 4; ++mt) {
            f32x4 d = {0.f,0.f,0.f,0.f};
            d = MFMA16(wk[mt*2], xk0, d, 0,0,0);
            ka[mt] = MFMA16(wk[mt*2+1], xk1, d, 0,0,0);
        }
#pragma unroll
        for (int mt = 0; mt < 4; ++mt) {
            f32x4 d = {0.f,0.f,0.f,0.f};
            d = MFMA16(wq[mt*2], xq0, d, 0,0,0);
            qa[mt] = MFMA16(wq[mt*2+1], xq1, d, 0,0,0);
            *reinterpret_cast<ushort4*>(qb + qbase + mt*16 + quad*4) = pack4(qa[mt], CEXP);
        }
#pragma unroll
        for (int mt = 0; mt < 4; ++mt) {
            f32x4 d = {0.f,0.f,0.f,0.f};
            d = MFMA16(wk[mt*2], xo0, d, 0,0,0);
            d = MFMA16(wk[mt*2+1], xo1, d, 0,0,0);
            *reinterpret_cast<ushort4*>(okb + qbase + mt*16 + quad*4) = pack4(d, 1.0f);
        }
        float p = 0.f;
#pragma unroll
        for (int mt = 0; mt < 4; ++mt)
            p += qa[mt][0]*ka[mt][0] + qa[mt][1]*ka[mt][1]
               + qa[mt][2]*ka[mt][2] + qa[mt][3]*ka[mt][3];
        p += __shfl_xor(p, 16);
        p += __shfl_xor(p, 32);
        if (lane < 16)
            ediag[((size_t)(nn * HH + h)) * LL + ll] = p;
    } else {
        const float4* vp = reinterpret_cast<const float4*>(values + xoff);
        const float4* op = reinterpret_cast<const float4*>(ovals  + xoff);
        float4 v0 = vp[0], v1 = vp[1], v2 = vp[8], v3 = vp[9];
        float4 o0 = op[0], o1 = op[1], o2 = op[8], o3 = op[9];
        bf16x8 wv[8];
#pragma unroll
        for (int f = 0; f < 8; ++f)
            wv[f] = ldfrag(wfrag + (size_t)((16 + f) * 64 + lane) * 8);
        bf16x8 xv0 = cvt8v(v0, v1), xv1 = cvt8v(v2, v3);
        bf16x8 xo0 = cvt8v(o0, o1), xo1 = cvt8v(o2, o3);
#pragma unroll
        for (int mt = 0; mt < 4; ++mt) {
            f32x4 d = {0.f,0.f,0.f,0.f};
            d = MFMA16(wv[mt*2], xv0, d, 0,0,0);
            d = MFMA16(wv[mt*2+1], xv1, d, 0,0,0);
            *reinterpret_cast<ushort4*>(vb + vbase + mt*16 + quad*4) = pack4(d, 1.0f);
        }
#pragma unroll
        for (int mt = 0; mt < 4; ++mt) {
            f32x4 d = {0.f,0.f,0.f,0.f};
            d = MFMA16(wv[mt*2], xo0, d, 0,0,0);
            d = MFMA16(wv[mt*2+1], xo1, d, 0,0,0);
            *reinterpret_cast<ushort4*>(ovb + vbase + mt*16 + quad*4) = pack4(d, 1.0f);
        }
    }
}

// ---------------------------------------------------------------------------
// K2: partial row-sums of exp(E/32) via MFMA, load-balanced.
// ---------------------------------------------------------------------------
__global__ __launch_bounds__(256) void zrow_part(
    const unsigned short* __restrict__ qb, const unsigned short* __restrict__ okb,
    float* __restrict__ Zbuf)
{
    const int px = blockIdx.x;
    const int pair = px >> 2;
    const int s = px & 3;
    const int nh = blockIdx.y;
    const int t = threadIdx.x;
    const int w = t >> 6;
    const int lane = t & 63;
    const int n = lane & 15;
    const int quad = lane >> 4;
    const size_t base = (size_t)nh * (LL * 64);
    const size_t nhL = (size_t)nh * LL;
    const int r0 = 4 * s + w;     // k-tile residue 0..15

#pragma unroll
    for (int half = 0; half < 2; ++half) {
        const int qt = half ? (31 - pair) : pair;
        const int kend = 4 * qt + 4;

        bf16x8 aq[4][2];
#pragma unroll
        for (int rt = 0; rt < 4; ++rt) {
            const unsigned short* p = qb + base + (size_t)(qt*64 + rt*16 + n) * 64 + quad * 8;
            aq[rt][0] = ldfrag(p); aq[rt][1] = ldfrag(p + 32);
        }

        float zacc[4][4];
#pragma unroll
        for (int rt = 0; rt < 4; ++rt)
#pragma unroll
            for (int r = 0; r < 4; ++r) zacc[rt][r] = 0.f;

        bf16x8 b0c, b1c;
        if (r0 < kend) {
            const unsigned short* kp = okb + base + (size_t)(r0*16 + n) * 64 + quad * 8;
            b0c = ldfrag(kp); b1c = ldfrag(kp + 32);
        }
        for (int kt = r0; kt < kend; kt += 16) {
            bf16x8 b0 = b0c, b1 = b1c;
            if (kt + 16 < kend) {
                const unsigned short* kp = okb + base + (size_t)((kt+16)*16 + n) * 64 + quad * 8;
                b0c = ldfrag(kp); b1c = ldfrag(kp + 32);
            }
            const int dk = kt - 4*qt;   // <0: all row-tiles full
#pragma unroll
            for (int rt = 0; rt < 4; ++rt) {
                if (rt < dk) continue;                    // fully masked
                f32x4 d = {0.f,0.f,0.f,0.f};
                d = MFMA16(aq[rt][0], b0, d, 0,0,0);
                d = MFMA16(aq[rt][1], b1, d, 0,0,0);
                if (rt == dk) {                            // diagonal tile
#pragma unroll
                    for (int r = 0; r < 4; ++r)
                        if (n < quad*4 + r) zacc[rt][r] += EXP2(d[r]);
                } else {
#pragma unroll
                    for (int r = 0; r < 4; ++r) zacc[rt][r] += EXP2(d[r]);
                }
            }
        }

#pragma unroll
        for (int rt = 0; rt < 4; ++rt)
#pragma unroll
            for (int r = 0; r < 4; ++r) {
                float z = zacc[rt][r];
                z += __shfl_xor(z, 1); z += __shfl_xor(z, 2);
                z += __shfl_xor(z, 4); z += __shfl_xor(z, 8);
                if (n == 0)
                    atomicAdd(&Zbuf[nhL + qt*64 + rt*16 + quad*4 + r], z);
            }
    }
}

// ---------------------------------------------------------------------------
// K2b: finalize invZ and diag_s from Zbuf + ediag.
// ---------------------------------------------------------------------------
__global__ __launch_bounds__(256) void zfin_kernel(
    const float* __restrict__ Zbuf, const float* __restrict__ ediag,
    float* __restrict__ invZ, float* __restrict__ diag_s)
{
    const int i = blockIdx.x * 256 + threadIdx.x;
    const float de = EXP2(ediag[i] * CEXP);
    const float iz = 1.f / (Zbuf[i] + de);
    invZ[i]   = iz;
    diag_s[i] = de * iz;
}

// ---------------------------------------------------------------------------
// K3: partial colsum[l] = sum_{q>l} exp(e[q,l]/32)*invZ[q], load-balanced.
// ---------------------------------------------------------------------------
__global__ __launch_bounds__(256) void colsum_part(
    const unsigned short* __restrict__ qb, const unsigned short* __restrict__ okb,
    const float* __restrict__ invZ, float* __restrict__ colsum)
{
    const int px = blockIdx.x;
    const int pair = px >> 2;
    const int s = px & 3;
    const int nh = blockIdx.y;
    const int t = threadIdx.x;
    const int w = t >> 6;
    const int lane = t & 63;
    const int n = lane & 15;
    const int quad = lane >> 4;
    const size_t base = (size_t)nh * (LL * 64);
    const size_t nhL = (size_t)nh * LL;
    const int r0 = 4 * s + w;     // residue 0..15

#pragma unroll
    for (int half = 0; half < 2; ++half) {
        const int lt = half ? (31 - pair) : pair;

        bf16x8 bl[4][2];
#pragma unroll
        for (int ct = 0; ct < 4; ++ct) {
            const unsigned short* p = okb + base + (size_t)(lt*64 + ct*16 + n) * 64 + quad * 8;
            bl[ct][0] = ldfrag(p); bl[ct][1] = ldfrag(p + 32);
        }

        float cacc[4] = {0.f, 0.f, 0.f, 0.f};

        const int kstart = 4*lt + r0;
        bf16x8 a0c, a1c; float izc = 0.f;
        if (kstart < KT16) {
            const unsigned short* qp = qb + base + (size_t)(kstart*16 + n) * 64 + quad * 8;
            a0c = ldfrag(qp); a1c = ldfrag(qp + 32);
            izc = invZ[nhL + kstart*16 + n];
        }
        for (int kt = kstart; kt < KT16; kt += 16) {
            bf16x8 a0 = a0c, a1 = a1c; const float izq = izc;
            if (kt + 16 < KT16) {
                const unsigned short* qp = qb + base + (size_t)((kt+16)*16 + n) * 64 + quad * 8;
                a0c = ldfrag(qp); a1c = ldfrag(qp + 32);
                izc = invZ[nhL + (kt+16)*16 + n];
            }
            float izr[4];
#pragma unroll
            for (int r = 0; r < 4; ++r) izr[r] = __shfl(izq, quad*4 + r);
            const int dk = kt - 4*lt;   // >=0 by construction
#pragma unroll
            for (int ct = 0; ct < 4; ++ct) {
                if (ct > dk) continue;                    // empty (q < l)
                f32x4 d = {0.f,0.f,0.f,0.f};
                d = MFMA16(a0, bl[ct][0], d, 0,0,0);
                d = MFMA16(a1, bl[ct][1], d, 0,0,0);
                if (ct == dk) {                            // diagonal tile: q>l only
#pragma unroll
                    for (int r = 0; r < 4; ++r)
                        if (quad*4 + r > n) cacc[ct] += EXP2(d[r]) * izr[r];
                } else {
#pragma unroll
                    for (int r = 0; r < 4; ++r) cacc[ct] += EXP2(d[r]) * izr[r];
                }
            }
        }

#pragma unroll
        for (int ct = 0; ct < 4; ++ct) {
            float c = cacc[ct];
            c += __shfl_down(c, 32);
            c += __shfl_down(c, 16);
            if (lane < 16)
                atomicAdd(&colsum[nhL + lt*64 + ct*16 + lane], c);
        }
    }
}

// ---------------------------------------------------------------------------
// K4: fc_w -> bf16
// ---------------------------------------------------------------------------
__global__ __launch_bounds__(256) void fcw_kernel(
    const float* __restrict__ fc_w, unsigned short* __restrict__ fcwb)
{
    const int idx = blockIdx.x * 1024 + threadIdx.x * 4;
    float4 wv = *reinterpret_cast<const float4*>(fc_w + idx);
    ushort4 o;
    o.x = f2bf(wv.x); o.y = f2bf(wv.y); o.z = f2bf(wv.z); o.w = f2bf(wv.w);
    *reinterpret_cast<ushort4*>(fcwb + idx) = o;
}

// ---------------------------------------------------------------------------
// K5: attb[row][d] = bf16( diag_s*vb + colsum*ovb )
// ---------------------------------------------------------------------------
__global__ __launch_bounds__(256) void att_kernel(
    const unsigned short* __restrict__ vb, const unsigned short* __restrict__ ovb,
    const float* __restrict__ diag_s, const float* __restrict__ colsum,
    unsigned short* __restrict__ attb)
{
    const int row = blockIdx.x;            // n*L + l
    const int nn = row >> 11, l = row & 2047;
    const int t = threadIdx.x;
    const int d0 = t * 4;
    const int h = t >> 4;                  // d0>>6
    const size_t nhl = ((size_t)(nn * HH + h)) * LL + l;
    const float ds = diag_s[nhl];
    const float cs = colsum[nhl];
    const ushort4 v  = *reinterpret_cast<const ushort4*>(vb  + (size_t)row * DD + d0);
    const ushort4 ov = *reinterpret_cast<const ushort4*>(ovb + (size_t)row * DD + d0);
    ushort4 o;
    o.x = f2bf(ds * bf2f(v.x) + cs * bf2f(ov.x));
    o.y = f2bf(ds * bf2f(v.y) + cs * bf2f(ov.y));
    o.z = f2bf(ds * bf2f(v.z) + cs * bf2f(ov.z));
    o.w = f2bf(ds * bf2f(v.w) + cs * bf2f(ov.w));
    *reinterpret_cast<ushort4*>(attb + (size_t)row * DD + d0) = o;
}

// ---------------------------------------------------------------------------
// K6: out = attb @ fcwb^T + fc_b. LDS-staged MFMA GEMM.
// Block tile 64(M) x 128(N), BK=64; grid (8 ct, 64 rt) = 512 blocks (2/CU).
// 4 waves as 2x2; wave tile 32x64 (2 m-frags x 4 n-frags = 16 MFMA / 12
// ds_read_b128 per BK iter). LDS pitch 72 (+8) -> 2-way read conflicts (free).
// Next iter's global chunks prefetched into VGPRs during compute.
// ---------------------------------------------------------------------------
__global__ __launch_bounds__(256) void out_kernel(
    const unsigned short* __restrict__ attb, const unsigned short* __restrict__ fcwb,
    const float* __restrict__ fc_b, float* __restrict__ out)
{
    __shared__ unsigned short As[64 * 72];    // [m 64][k 64] pitch 72
    __shared__ unsigned short Bs[128 * 72];   // [n 128][k 64] pitch 72

    const int ct = blockIdx.x;   // 0..7   col tile (128 cols)
    const int rt = blockIdx.y;   // 0..63  row tile (64 rows)
    const int t = threadIdx.x;
    const int w = t >> 6;
    const int lane = t & 63;
    const int n16 = lane & 15, quad = lane >> 4;
    const int wm = w >> 1;       // m half (32 rows)
    const int wn = w & 1;        // n half (64 cols)
    const int row0 = rt * 64, col0 = ct * 128;

    const unsigned short* aBase = attb + (size_t)row0 * DD;
    const unsigned short* bBase = fcwb + (size_t)col0 * DD;

    // staging map: thread t stages 16B chunks; chunk row = t>>3 (+32*i), col = (t&7)*8
    const int srow = t >> 3;          // 0..31
    const int scol = (t & 7) * 8;

    f32x4 acc[2][4];
#pragma unroll
    for (int mi = 0; mi < 2; ++mi)
#pragma unroll
        for (int ni = 0; ni < 4; ++ni) acc[mi][ni] = (f32x4){0.f,0.f,0.f,0.f};

    uint4 pa[2], pb[4];
#pragma unroll
    for (int i = 0; i < 2; ++i)
        pa[i] = *reinterpret_cast<const uint4*>(aBase + (size_t)(srow + 32*i) * DD + scol);
#pragma unroll
    for (int i = 0; i < 4; ++i)
        pb[i] = *reinterpret_cast<const uint4*>(bBase + (size_t)(srow + 32*i) * DD + scol);

    for (int k0 = 0; k0 < DD; k0 += 64) {
        __syncthreads();                       // prior frag reads done
#pragma unroll
        for (int i = 0; i < 2; ++i)
            *reinterpret_cast<uint4*>(As + (srow + 32*i) * 72 + scol) = pa[i];
#pragma unroll
        for (int i = 0; i < 4; ++i)
            *reinterpret_cast<uint4*>(Bs + (srow + 32*i) * 72 + scol) = pb[i];
        __syncthreads();

        if (k0 + 64 < DD) {                    // prefetch next BK into VGPRs
#pragma unroll
            for (int i = 0; i < 2; ++i)
                pa[i] = *reinterpret_cast<const uint4*>(aBase + (size_t)(srow + 32*i) * DD + k0 + 64 + scol);
#pragma unroll
            for (int i = 0; i < 4; ++i)
                pb[i] = *reinterpret_cast<const uint4*>(bBase + (size_t)(srow + 32*i) * DD + k0 + 64 + scol);
        }

#pragma unroll
        for (int kk = 0; kk < 2; ++kk) {
            bf16x8 af[2], bfr[4];
#pragma unroll
            for (int mi = 0; mi < 2; ++mi)
                af[mi] = ldfrag(As + (wm*32 + mi*16 + n16) * 72 + kk*32 + quad*8);
#pragma unroll
            for (int ni = 0; ni < 4; ++ni)
                bfr[ni] = ldfrag(Bs + (wn*64 + ni*16 + n16) * 72 + kk*32 + quad*8);
#pragma unroll
            for (int mi = 0; mi < 2; ++mi)
#pragma unroll
                for (int ni = 0; ni < 4; ++ni)
                    acc[mi][ni] = MFMA16(af[mi], bfr[ni], acc[mi][ni], 0,0,0);
        }
    }

#pragma unroll
    for (int ni = 0; ni < 4; ++ni) {
        const int col = col0 + wn*64 + ni*16 + n16;
        const float bias = fc_b[col];
#pragma unroll
        for (int mi = 0; mi < 2; ++mi)
#pragma unroll
            for (int r = 0; r < 4; ++r) {
                const int grow = row0 + wm*32 + mi*16 + quad*4 + r;
                out[(size_t)grow * DD + col] = acc[mi][ni][r] + bias;
            }
    }
}

// ---------------------------------------------------------------------------
extern "C" void kernel_launch(void* const* d_in, const int* in_sizes, int n_in,
                              void* d_out, int out_size, void* d_ws, size_t ws_size,
                              hipStream_t stream) {
    const float* values = (const float*)d_in[0];
    const float* keys   = (const float*)d_in[1];
    const float* query  = (const float*)d_in[2];
    const float* ovals  = (const float*)d_in[3];
    const float* okeys  = (const float*)d_in[4];
    const float* Wv     = (const float*)d_in[5];
    const float* Wk     = (const float*)d_in[6];
    const float* Wq     = (const float*)d_in[7];
    const float* fc_w   = (const float*)d_in[8];
    const float* fc_b   = (const float*)d_in[9];
    // d_in[10]: mask — HIST==L makes it pure causal, handled analytically.
    float* out = (float*)d_out;

    float* ws      = (float*)d_ws;
    float* ediag   = ws;                     // 65536 f32
    float* Zbuf    = ediag + 65536;          // 65536 f32 (atomic accum)
    float* colsum  = Zbuf + 65536;           // 65536 f32 (atomic accum)
    float* invZ    = colsum + 65536;
    float* diag_s  = invZ + 65536;
    unsigned short* qb   = (unsigned short*)(diag_s + 65536);  // [32][2048][64] bf16
    unsigned short* okb  = qb   + 4194304;
    unsigned short* vb   = okb  + 4194304;   // [n][l][1024] bf16
    unsigned short* ovb  = vb   + 4194304;
    unsigned short* attb = ovb  + 4194304;   // [4096][1024] bf16
    unsigned short* fcwb = attb + 4194304;   // [1024][1024] bf16
    unsigned short* wfrag = fcwb + 1048576;  // 3*8*64*8 = 12288 bf16 (24 KB)

    // zero the two atomic accumulators (Zbuf, colsum are adjacent)
    hipMemsetAsync(Zbuf, 0, 2 * 65536 * sizeof(float), stream);

    wcvt_kernel<<<dim3(6), 256, 0, stream>>>(Wk, Wq, Wv, wfrag);
    fcw_kernel<<<dim3(1024), 256, 0, stream>>>(fc_w, fcwb);
    proj_kernel<<<dim3(64, 16, 2), 256, 0, stream>>>(
        values, keys, query, ovals, okeys, wfrag, qb, okb, vb, ovb, ediag);
    zrow_part<<<dim3(64, NHH), 256, 0, stream>>>(qb, okb, Zbuf);
    zfin_kernel<<<dim3(256), 256, 0, stream>>>(Zbuf, ediag, invZ, diag_s);
    colsum_part<<<dim3(64, NHH), 256, 0, stream>>>(qb, okb, invZ, colsum);
    att_kernel<<<dim3(NB * LL), 256, 0, stream>>>(vb, ovb, diag_s, colsum, attb);
    out_kernel<<<dim3(8, 64), 256, 0, stream>>>(attb, fcwb, fc_b, out);
}